// Round 8
// baseline (209.447 us; speedup 1.0000x reference)
//
#include <hip/hip_runtime.h>

// MultiHeadAttention: B=2,S=2048,D=1024,H=16,dh=64. fp32 in/out, bf16 MFMA internally.
// R8: attention q-tile 64 -> 128 rows (wave owns 32 q-rows in 2 subtiles): halves per-row
// K/V LDS reads, halves iterations/barriers; final key-block skips fully-masked lower
// subtile; 512 blocks in LPT (heavy-first) order. GEMMs/prep unchanged from R7.

typedef __attribute__((ext_vector_type(8))) short short8;
typedef __attribute__((ext_vector_type(4))) float f32x4;

#define MFMA_B16(a, b, c) __builtin_amdgcn_mfma_f32_16x16x32_bf16(a, b, c, 0, 0, 0)

#if __has_builtin(__builtin_amdgcn_exp2f)
#define EXP2(x) __builtin_amdgcn_exp2f(x)
#else
#define EXP2(x) exp2f(x)
#endif

static __device__ __forceinline__ unsigned short f2bf(float f) {
    union { float f; unsigned int u; } v;
    v.f = f;
    unsigned int r = (v.u + 0x7fffu + ((v.u >> 16) & 1u)) >> 16;
    return (unsigned short)r;
}

static __device__ __forceinline__ unsigned int pk_bf16(float a, float b) {
#if __has_builtin(__builtin_amdgcn_cvt_pk_bf16_f32)
    typedef __bf16 bf2 __attribute__((ext_vector_type(2)));
    union { bf2 v; unsigned int u; } c;
    c.v = __builtin_amdgcn_cvt_pk_bf16_f32(a, b);
    return c.u;
#else
    return (unsigned int)f2bf(a) | ((unsigned int)f2bf(b) << 16);
#endif
}

static __device__ __forceinline__ void gl_lds16(const void* g, void* l) {
    __builtin_amdgcn_global_load_lds(
        (const __attribute__((address_space(1))) unsigned int*)g,
        (__attribute__((address_space(3))) unsigned int*)l, 16, 0, 0);
}

// ---------------- fused prep: convert x + transpose both weights ----------------
__global__ __launch_bounds__(256) void prep_kernel(const float4* __restrict__ x,
                                                   ushort4* __restrict__ xb,
                                                   const float* __restrict__ wqkv,
                                                   unsigned short* __restrict__ wqkvT,
                                                   const float* __restrict__ wproj,
                                                   unsigned short* __restrict__ wprojT) {
    const int bid = blockIdx.x;
    if (bid < 4096) {
        int i = bid * 256 + threadIdx.x;
        float4 v = x[i];
        ushort4 o;
        o.x = f2bf(v.x); o.y = f2bf(v.y); o.z = f2bf(v.z); o.w = f2bf(v.w);
        xb[i] = o;
        return;
    }
    __shared__ float t[32][33];
    const float* in;
    unsigned short* out;
    int R, C, bx, by;
    if (bid < 4096 + 3072) {
        int g = bid - 4096;
        in = wqkv; out = wqkvT; R = 1024; C = 3072;
        bx = g % 96; by = g / 96;
    } else {
        int g = bid - 7168;
        in = wproj; out = wprojT; R = 1024; C = 1024;
        bx = g & 31; by = g >> 5;
    }
    const int c0 = bx * 32, r0 = by * 32;
    const int xx = threadIdx.x & 31, yy0 = threadIdx.x >> 5;
    #pragma unroll
    for (int yy = yy0; yy < 32; yy += 8)
        t[yy][xx] = in[(size_t)(r0 + yy) * C + (c0 + xx)];
    __syncthreads();
    #pragma unroll
    for (int yy = yy0; yy < 32; yy += 8)
        out[(size_t)(c0 + yy) * R + (r0 + xx)] = f2bf(t[xx][yy]);
}

// ---------------- QKV GEMM: C[4096x3072] = A * Bt^T ----------------
__global__ __launch_bounds__(256) void gemm_qkv_kernel(const unsigned short* __restrict__ A,
                                                       const unsigned short* __restrict__ Bt,
                                                       const float* __restrict__ bias,
                                                       unsigned short* __restrict__ q,
                                                       unsigned short* __restrict__ k,
                                                       unsigned short* __restrict__ vT) {
    __shared__ unsigned short As[128 * 64];
    __shared__ unsigned short Bs[128 * 64];
    const int tid = threadIdx.x;
    const int lane = tid & 63, wave = tid >> 6;
    const int l15 = lane & 15, quad = lane >> 4;
    const int wm = wave >> 1, wn = wave & 1;
    const int row0 = blockIdx.y * 128, col0 = blockIdx.x * 128;
    const int K = 1024;
    const bool isV = (blockIdx.x >= 16);

    int srow[4], scol[4], sdst[4];
    #pragma unroll
    for (int h = 0; h < 4; ++h) {
        int D = h * 256 + wave * 64 + lane;
        srow[h] = D >> 3;
        scol[h] = ((D & 7) ^ (srow[h] & 7)) * 8;
        sdst[h] = (h * 256 + wave * 64) * 8;
    }

    f32x4 acc[4][4] = {};

    for (int kt = 0; kt < K; kt += 64) {
        #pragma unroll
        for (int h = 0; h < 4; ++h) {
            gl_lds16(&A[(size_t)(row0 + srow[h]) * K + kt + scol[h]], &As[sdst[h]]);
            gl_lds16(&Bt[(size_t)(col0 + srow[h]) * K + kt + scol[h]], &Bs[sdst[h]]);
        }
        __syncthreads();
        #pragma unroll
        for (int kk = 0; kk < 2; ++kk) {
            short8 af[4], bf[4];
            #pragma unroll
            for (int i = 0; i < 4; ++i) {
                int r = wm * 64 + i * 16 + l15;
                af[i] = *(const short8*)&As[r * 64 + (((kk * 4 + quad) ^ (r & 7)) * 8)];
            }
            #pragma unroll
            for (int j = 0; j < 4; ++j) {
                int r = wn * 64 + j * 16 + l15;
                bf[j] = *(const short8*)&Bs[r * 64 + (((kk * 4 + quad) ^ (r & 7)) * 8)];
            }
            if (isV) {
                #pragma unroll
                for (int i = 0; i < 4; ++i)
                    #pragma unroll
                    for (int j = 0; j < 4; ++j)
                        acc[i][j] = MFMA_B16(af[i], bf[j], acc[i][j]);  // C
            } else {
                #pragma unroll
                for (int i = 0; i < 4; ++i)
                    #pragma unroll
                    for (int j = 0; j < 4; ++j)
                        acc[i][j] = MFMA_B16(bf[j], af[i], acc[i][j]);  // C^T
            }
        }
        __syncthreads();
    }

    const int b = row0 >> 11;
    const int s0 = row0 & 2047;
    const float* bb = bias + col0 + wn * 64;

    if (!isV) {
        const int which = blockIdx.x >> 3;  // 0=Q, 1=K
        unsigned short* dst = which ? k : q;
        const float scale = which ? 1.0f : 0.1803368867f;  // 1/8 * log2(e) for Q
        const int hh = ((blockIdx.x & 7) << 1) + wn;
        #pragma unroll
        for (int i = 0; i < 4; ++i) {
            const int s = s0 + wm * 64 + i * 16 + l15;
            unsigned short* drow = dst + ((size_t)((b * 16 + hh) * 2048 + s)) * 64;
            #pragma unroll
            for (int j = 0; j < 4; ++j) {
                float4 b4 = ((const float4*)bb)[j * 4 + quad];
                uint2 pv;
                pv.x = pk_bf16((acc[i][j][0] + b4.x) * scale, (acc[i][j][1] + b4.y) * scale);
                pv.y = pk_bf16((acc[i][j][2] + b4.z) * scale, (acc[i][j][3] + b4.w) * scale);
                *(uint2*)&drow[j * 16 + quad * 4] = pv;
            }
        }
    } else {
        const int hh = ((blockIdx.x - 16) << 1) + wn;
        #pragma unroll
        for (int j = 0; j < 4; ++j) {
            const int d = j * 16 + l15;
            const float bv = bb[d];
            unsigned short* drow = vT + ((size_t)((b * 16 + hh) * 64 + d)) * 2048 + s0;
            #pragma unroll
            for (int i = 0; i < 4; ++i) {
                uint2 pv;
                pv.x = pk_bf16(acc[i][j][0] + bv, acc[i][j][1] + bv);
                pv.y = pk_bf16(acc[i][j][2] + bv, acc[i][j][3] + bv);
                *(uint2*)&drow[wm * 64 + i * 16 + quad * 4] = pv;
            }
        }
    }
}

// ---------------- proj GEMM: out[4096x1024] fp32 = A * Bt^T + bias ----------------
__global__ __launch_bounds__(256) void gemm_proj_kernel(const unsigned short* __restrict__ A,
                                                        const unsigned short* __restrict__ Bt,
                                                        const float* __restrict__ bias,
                                                        float* __restrict__ out) {
    __shared__ unsigned short As[128 * 64];
    __shared__ unsigned short Bs[64 * 64];
    const int tid = threadIdx.x;
    const int lane = tid & 63, wave = tid >> 6;
    const int l15 = lane & 15, quad = lane >> 4;
    const int wm = wave >> 1, wn = wave & 1;
    const int row0 = blockIdx.y * 128, col0 = blockIdx.x * 64;
    const int K = 1024;

    int srow[4], scol[4], sdst[4];
    #pragma unroll
    for (int h = 0; h < 4; ++h) {
        int D = h * 256 + wave * 64 + lane;
        srow[h] = D >> 3;
        scol[h] = ((D & 7) ^ (srow[h] & 7)) * 8;
        sdst[h] = (h * 256 + wave * 64) * 8;
    }

    f32x4 acc[4][2] = {};

    for (int kt = 0; kt < K; kt += 64) {
        #pragma unroll
        for (int h = 0; h < 4; ++h)
            gl_lds16(&A[(size_t)(row0 + srow[h]) * K + kt + scol[h]], &As[sdst[h]]);
        #pragma unroll
        for (int h = 0; h < 2; ++h)
            gl_lds16(&Bt[(size_t)(col0 + srow[h]) * K + kt + scol[h]], &Bs[sdst[h]]);
        __syncthreads();
        #pragma unroll
        for (int kk = 0; kk < 2; ++kk) {
            short8 af[4], bf[2];
            #pragma unroll
            for (int i = 0; i < 4; ++i) {
                int r = wm * 64 + i * 16 + l15;
                af[i] = *(const short8*)&As[r * 64 + (((kk * 4 + quad) ^ (r & 7)) * 8)];
            }
            #pragma unroll
            for (int j = 0; j < 2; ++j) {
                int r = wn * 32 + j * 16 + l15;
                bf[j] = *(const short8*)&Bs[r * 64 + (((kk * 4 + quad) ^ (r & 7)) * 8)];
            }
            #pragma unroll
            for (int i = 0; i < 4; ++i)
                #pragma unroll
                for (int j = 0; j < 2; ++j)
                    acc[i][j] = MFMA_B16(bf[j], af[i], acc[i][j]);  // C^T
        }
        __syncthreads();
    }

    const float* bb = bias + col0 + wn * 32;
    #pragma unroll
    for (int i = 0; i < 4; ++i) {
        const int row = row0 + wm * 64 + i * 16 + l15;
        #pragma unroll
        for (int j = 0; j < 2; ++j) {
            float4 b4 = ((const float4*)bb)[j * 4 + quad];
            float4 ov;
            ov.x = acc[i][j][0] + b4.x;
            ov.y = acc[i][j][1] + b4.y;
            ov.z = acc[i][j][2] + b4.z;
            ov.w = acc[i][j][3] + b4.w;
            *(float4*)&out[(size_t)row * 1024 + col0 + wn * 32 + j * 16 + quad * 4] = ov;
        }
    }
}

// ---------------- flash attention R8: 128-row q-tiles, 2 subtiles/wave ----------------
// Block = 4 waves = one 128-row q-tile; wave owns q-rows q0+l15 (sub A) and q0+64+l15 (sub B).
// 512 blocks in LPT order (t = 15 - (bid>>5), heavy first). Final key-block skips sub A
// (fully causal-masked). Fixed-max softmax, forcing in C-init, lsum via ones-MFMA.
__global__ __launch_bounds__(256) void attn_kernel(const unsigned short* __restrict__ Q,
                                                   const unsigned short* __restrict__ Kg,
                                                   const unsigned short* __restrict__ Vt,
                                                   const int* __restrict__ idx,
                                                   const float* __restrict__ weight,
                                                   const int* __restrict__ forcing,
                                                   unsigned short* __restrict__ O) {
    __shared__ unsigned short Ks[2][4096];
    __shared__ unsigned short Vs[2][4096];
    __shared__ unsigned short Pw[4][2048];   // per-wave: sub A at 0, sub B at 1024

    const int tid = threadIdx.x;
    const int lane = tid & 63, wave = tid >> 6;
    const int l15 = lane & 15, quad = lane >> 4;
    const int bid = blockIdx.x;
    const int t = 15 - (bid >> 5);           // LPT: heaviest tiles first
    const int bh = bid & 31;
    const int b = bh >> 4, hh = bh & 15;
    const unsigned short* Qb = Q + (size_t)bh * 2048 * 64;
    const unsigned short* Kh = Kg + (size_t)bh * 2048 * 64;
    const unsigned short* Vh = Vt + (size_t)bh * 2048 * 64;

    const int idxb = idx[b];
    const float lw = (forcing[0] != 0) ? __log2f(weight[0]) : 0.0f;

    const int L0 = wave * 128 + lane;
    const int rS = L0 >> 3;
    const int cS = (L0 & 7) ^ (rS & 7);
    const int ldsOffJ0 = (wave * 128) * 8;
    const int ldsOffJ1 = (wave * 128 + 64) * 8;

    const int q0 = t * 128 + wave * 16;
    const int qrowA = q0 + l15;
    const int qrowB = q0 + 64 + l15;

    short8 aqA0 = *(const short8*)&Qb[(q0 + l15) * 64 + quad * 8];
    short8 aqA1 = *(const short8*)&Qb[(q0 + l15) * 64 + 32 + quad * 8];
    short8 aqB0 = *(const short8*)&Qb[(q0 + 64 + l15) * 64 + quad * 8];
    short8 aqB1 = *(const short8*)&Qb[(q0 + 64 + l15) * 64 + 32 + quad * 8];

    const short8 ones8 = {0x3F80, 0x3F80, 0x3F80, 0x3F80, 0x3F80, 0x3F80, 0x3F80, 0x3F80};

    f32x4 oA[4] = {}, oB[4] = {};
    f32x4 lsA = {}, lsB = {};

    const int nkb = 2 * t + 2;

    {   // prologue: stage block 0 into buf 0
        const unsigned short* kg = Kh + (size_t)rS * 64 + cS * 8;
        const unsigned short* vg = Vh + (size_t)rS * 2048 + cS * 8;
        gl_lds16(kg,            &Ks[0][ldsOffJ0]);
        gl_lds16(kg + 8 * 64,   &Ks[0][ldsOffJ1]);
        gl_lds16(vg,            &Vs[0][ldsOffJ0]);
        gl_lds16(vg + 8 * 2048, &Vs[0][ldsOffJ1]);
    }
    __syncthreads();

    unsigned short* const pwb = &Pw[wave][0];
    const int pwr = l15 * 64;
    const int pa7 = l15 & 7;

    for (int kb = 0; kb < nkb; ++kb) {
        const int cur = kb & 1;
        const int kbase = kb * 64;
        if (kb + 1 < nkb) {
            const int nb = kbase + 64;
            const unsigned short* kg = Kh + (size_t)(nb + rS) * 64 + cS * 8;
            const unsigned short* vg = Vh + (size_t)rS * 2048 + nb + cS * 8;
            gl_lds16(kg,            &Ks[cur ^ 1][ldsOffJ0]);
            gl_lds16(kg + 8 * 64,   &Ks[cur ^ 1][ldsOffJ1]);
            gl_lds16(vg,            &Vs[cur ^ 1][ldsOffJ0]);
            gl_lds16(vg + 8 * 2048, &Vs[cur ^ 1][ldsOffJ1]);
        }

        const bool liveA = (kb + 1 < nkb);   // sub A fully masked in last block
        const bool diagA = (kb + 2 == nkb);
        const bool diagB = (kb + 1 == nkb);

        // ---- forcing C-init (key-dependent only; shared by A and B) ----
        const bool fullF = (kbase >= idxb);
        const bool bndF = (!fullF) && (kbase + 63 >= idxb);
        const float zu = fullF ? lw : 0.0f;
        f32x4 zi[4];
        #pragma unroll
        for (int kt = 0; kt < 4; ++kt) {
            if (!bndF) {
                zi[kt][0] = zu; zi[kt][1] = zu; zi[kt][2] = zu; zi[kt][3] = zu;
            } else {
                #pragma unroll
                for (int r = 0; r < 4; ++r)
                    zi[kt][r] = (kbase + kt * 16 + quad * 4 + r >= idxb) ? lw : 0.0f;
            }
        }

        // ---- S^T for both subtiles ----
        f32x4 sA[4], sB[4];
        #pragma unroll
        for (int kt = 0; kt < 4; ++kt) {
            const int row = kt * 16 + l15;
            short8 k0 = *(const short8*)&Ks[cur][row * 64 + ((quad ^ (row & 7)) * 8)];
            short8 k1 = *(const short8*)&Ks[cur][row * 64 + (((4 + quad) ^ (row & 7)) * 8)];
            if (liveA) {
                f32x4 z = zi[kt];
                z = MFMA_B16(k0, aqA0, z);
                z = MFMA_B16(k1, aqA1, z);
                sA[kt] = z;
            }
            f32x4 z = zi[kt];
            z = MFMA_B16(k0, aqB0, z);
            z = MFMA_B16(k1, aqB1, z);
            sB[kt] = z;
        }

        // ---- causal diagonals ----
        if (diagA) {
            #pragma unroll
            for (int kt = 0; kt < 4; ++kt)
                #pragma unroll
                for (int r = 0; r < 4; ++r)
                    if (kbase + kt * 16 + quad * 4 + r > qrowA) sA[kt][r] = -3.0e38f;
        }
        if (diagB) {
            #pragma unroll
            for (int kt = 0; kt < 4; ++kt)
                #pragma unroll
                for (int r = 0; r < 4; ++r)
                    if (kbase + kt * 16 + quad * 4 + r > qrowB) sB[kt][r] = -3.0e38f;
        }

        // ---- p = exp2(s); pack & write P to per-wave swizzled LDS ----
        if (liveA) {
            #pragma unroll
            for (int kt = 0; kt < 4; ++kt) {
                #pragma unroll
                for (int r = 0; r < 4; ++r) sA[kt][r] = EXP2(sA[kt][r]);
                unsigned int* pw = (unsigned int*)&pwb[pwr +
                    (((kt * 2 + (quad >> 1)) ^ pa7) * 8) + (quad & 1) * 4];
                pw[0] = pk_bf16(sA[kt][0], sA[kt][1]);
                pw[1] = pk_bf16(sA[kt][2], sA[kt][3]);
            }
        }
        #pragma unroll
        for (int kt = 0; kt < 4; ++kt) {
            #pragma unroll
            for (int r = 0; r < 4; ++r) sB[kt][r] = EXP2(sB[kt][r]);
            unsigned int* pw = (unsigned int*)&pwb[1024 + pwr +
                (((kt * 2 + (quad >> 1)) ^ pa7) * 8) + (quad & 1) * 4];
            pw[0] = pk_bf16(sB[kt][0], sB[kt][1]);
            pw[1] = pk_bf16(sB[kt][2], sB[kt][3]);
        }

        // ---- B-frags + lsum ----
        short8 bpA0, bpA1;
        if (liveA) {
            bpA0 = *(const short8*)&pwb[pwr + ((quad ^ pa7) * 8)];
            bpA1 = *(const short8*)&pwb[pwr + (((4 + quad) ^ pa7) * 8)];
            lsA = MFMA_B16(ones8, bpA0, lsA);
            lsA = MFMA_B16(ones8, bpA1, lsA);
        }
        short8 bpB0 = *(const short8*)&pwb[1024 + pwr + ((quad ^ pa7) * 8)];
        short8 bpB1 = *(const short8*)&pwb[1024 + pwr + (((4 + quad) ^ pa7) * 8)];
        lsB = MFMA_B16(ones8, bpB0, lsB);
        lsB = MFMA_B16(ones8, bpB1, lsB);

        // ---- O^T += V^T P^T (V fragments shared by both subtiles) ----
        #pragma unroll
        for (int dt = 0; dt < 4; ++dt) {
            const int row = dt * 16 + l15;
            short8 vf0 = *(const short8*)&Vs[cur][row * 64 + ((quad ^ (row & 7)) * 8)];
            short8 vf1 = *(const short8*)&Vs[cur][row * 64 + (((4 + quad) ^ (row & 7)) * 8)];
            if (liveA) {
                f32x4 oo = oA[dt];
                oo = MFMA_B16(vf0, bpA0, oo);
                oo = MFMA_B16(vf1, bpA1, oo);
                oA[dt] = oo;
            }
            f32x4 oo = oB[dt];
            oo = MFMA_B16(vf0, bpB0, oo);
            oo = MFMA_B16(vf1, bpB1, oo);
            oB[dt] = oo;
        }

        __syncthreads();
    }

    // ---- epilogue: O^T -> O via wave-private LDS transpose (K buffers dead) ----
    unsigned short* sc = &Ks[0][0] + wave * 1152;  // 16 rows x 72 stride (wave-private)
    {
        const float inv = 1.0f / lsA[0];
        #pragma unroll
        for (int dt = 0; dt < 4; ++dt)
            #pragma unroll
            for (int r = 0; r < 4; ++r)
                sc[l15 * 72 + dt * 16 + quad * 4 + r] = f2bf(oA[dt][r] * inv);
        const size_t rowoff = ((size_t)(b * 2048 + q0 + l15)) * 1024 + hh * 64;
        #pragma unroll
        for (int h = 0; h < 2; ++h) {
            short8 v8 = *(const short8*)&sc[l15 * 72 + quad * 16 + h * 8];
            *(short8*)&O[rowoff + quad * 16 + h * 8] = v8;
        }
    }
    {
        const float inv = 1.0f / lsB[0];
        #pragma unroll
        for (int dt = 0; dt < 4; ++dt)
            #pragma unroll
            for (int r = 0; r < 4; ++r)
                sc[l15 * 72 + dt * 16 + quad * 4 + r] = f2bf(oB[dt][r] * inv);
        const size_t rowoff = ((size_t)(b * 2048 + q0 + 64 + l15)) * 1024 + hh * 64;
        #pragma unroll
        for (int h = 0; h < 2; ++h) {
            short8 v8 = *(const short8*)&sc[l15 * 72 + quad * 16 + h * 8];
            *(short8*)&O[rowoff + quad * 16 + h * 8] = v8;
        }
    }
}

extern "C" void kernel_launch(void* const* d_in, const int* in_sizes, int n_in,
                              void* d_out, int out_size, void* d_ws, size_t ws_size,
                              hipStream_t stream) {
    const float* x        = (const float*)d_in[0];
    const int*   idx      = (const int*)d_in[1];
    const float* weight   = (const float*)d_in[2];
    const int*   forcing  = (const int*)d_in[3];
    const float* w_qkv    = (const float*)d_in[4];
    const float* b_qkv    = (const float*)d_in[5];
    const float* w_proj   = (const float*)d_in[6];
    const float* b_proj   = (const float*)d_in[7];
    float* out = (float*)d_out;

    char* ws = (char*)d_ws;
    unsigned short* xb      = (unsigned short*)(ws);              // 8 MB (reused: attn_out)
    unsigned short* wqkvT   = (unsigned short*)(ws + 8388608);    // 6 MB
    unsigned short* wprojT  = (unsigned short*)(ws + 14680064);   // 2 MB
    unsigned short* qbuf    = (unsigned short*)(ws + 16777216);   // 8 MB
    unsigned short* kbuf    = (unsigned short*)(ws + 25165824);   // 8 MB
    unsigned short* vTbuf   = (unsigned short*)(ws + 33554432);   // 8 MB
    unsigned short* attn_out = xb;  // xb dead after gemm_qkv

    prep_kernel<<<8192, 256, 0, stream>>>((const float4*)x, (ushort4*)xb,
                                          w_qkv, wqkvT, w_proj, wprojT);
    gemm_qkv_kernel<<<dim3(24, 32), 256, 0, stream>>>(xb, wqkvT, b_qkv, qbuf, kbuf, vTbuf);
    attn_kernel<<<512, 256, 0, stream>>>(qbuf, kbuf, vTbuf, idx, weight, forcing, attn_out);
    gemm_proj_kernel<<<dim3(16, 32), 256, 0, stream>>>(attn_out, wprojT, b_proj, out);
}

// Round 9
// 194.837 us; speedup vs baseline: 1.0750x; 1.0750x over previous
//
#include <hip/hip_runtime.h>

// MultiHeadAttention: B=2,S=2048,D=1024,H=16,dh=64. fp32 in/out, bf16 MFMA internally.
// R9: attention — R7's 64-row q-tiles / 1024-block balanced grid restored, but blocks are
// 128 threads (2 waves); each wave covers 32 q-rows as two 16-row subtiles, reusing each
// K/V LDS fragment for both (halves LDS read traffic per q-row, halves barrier width).
// GEMMs/prep unchanged from R7 (swapped-MFMA epilogues, fused prep).

typedef __attribute__((ext_vector_type(8))) short short8;
typedef __attribute__((ext_vector_type(4))) float f32x4;

#define MFMA_B16(a, b, c) __builtin_amdgcn_mfma_f32_16x16x32_bf16(a, b, c, 0, 0, 0)

#if __has_builtin(__builtin_amdgcn_exp2f)
#define EXP2(x) __builtin_amdgcn_exp2f(x)
#else
#define EXP2(x) exp2f(x)
#endif

static __device__ __forceinline__ unsigned short f2bf(float f) {
    union { float f; unsigned int u; } v;
    v.f = f;
    unsigned int r = (v.u + 0x7fffu + ((v.u >> 16) & 1u)) >> 16;
    return (unsigned short)r;
}

static __device__ __forceinline__ unsigned int pk_bf16(float a, float b) {
#if __has_builtin(__builtin_amdgcn_cvt_pk_bf16_f32)
    typedef __bf16 bf2 __attribute__((ext_vector_type(2)));
    union { bf2 v; unsigned int u; } c;
    c.v = __builtin_amdgcn_cvt_pk_bf16_f32(a, b);
    return c.u;
#else
    return (unsigned int)f2bf(a) | ((unsigned int)f2bf(b) << 16);
#endif
}

static __device__ __forceinline__ void gl_lds16(const void* g, void* l) {
    __builtin_amdgcn_global_load_lds(
        (const __attribute__((address_space(1))) unsigned int*)g,
        (__attribute__((address_space(3))) unsigned int*)l, 16, 0, 0);
}

// ---------------- fused prep: convert x + transpose both weights ----------------
__global__ __launch_bounds__(256) void prep_kernel(const float4* __restrict__ x,
                                                   ushort4* __restrict__ xb,
                                                   const float* __restrict__ wqkv,
                                                   unsigned short* __restrict__ wqkvT,
                                                   const float* __restrict__ wproj,
                                                   unsigned short* __restrict__ wprojT) {
    const int bid = blockIdx.x;
    if (bid < 4096) {
        int i = bid * 256 + threadIdx.x;
        float4 v = x[i];
        ushort4 o;
        o.x = f2bf(v.x); o.y = f2bf(v.y); o.z = f2bf(v.z); o.w = f2bf(v.w);
        xb[i] = o;
        return;
    }
    __shared__ float t[32][33];
    const float* in;
    unsigned short* out;
    int R, C, bx, by;
    if (bid < 4096 + 3072) {
        int g = bid - 4096;
        in = wqkv; out = wqkvT; R = 1024; C = 3072;
        bx = g % 96; by = g / 96;
    } else {
        int g = bid - 7168;
        in = wproj; out = wprojT; R = 1024; C = 1024;
        bx = g & 31; by = g >> 5;
    }
    const int c0 = bx * 32, r0 = by * 32;
    const int xx = threadIdx.x & 31, yy0 = threadIdx.x >> 5;
    #pragma unroll
    for (int yy = yy0; yy < 32; yy += 8)
        t[yy][xx] = in[(size_t)(r0 + yy) * C + (c0 + xx)];
    __syncthreads();
    #pragma unroll
    for (int yy = yy0; yy < 32; yy += 8)
        out[(size_t)(c0 + yy) * R + (r0 + xx)] = f2bf(t[xx][yy]);
}

// ---------------- QKV GEMM: C[4096x3072] = A * Bt^T ----------------
__global__ __launch_bounds__(256) void gemm_qkv_kernel(const unsigned short* __restrict__ A,
                                                       const unsigned short* __restrict__ Bt,
                                                       const float* __restrict__ bias,
                                                       unsigned short* __restrict__ q,
                                                       unsigned short* __restrict__ k,
                                                       unsigned short* __restrict__ vT) {
    __shared__ unsigned short As[128 * 64];
    __shared__ unsigned short Bs[128 * 64];
    const int tid = threadIdx.x;
    const int lane = tid & 63, wave = tid >> 6;
    const int l15 = lane & 15, quad = lane >> 4;
    const int wm = wave >> 1, wn = wave & 1;
    const int row0 = blockIdx.y * 128, col0 = blockIdx.x * 128;
    const int K = 1024;
    const bool isV = (blockIdx.x >= 16);

    int srow[4], scol[4], sdst[4];
    #pragma unroll
    for (int h = 0; h < 4; ++h) {
        int D = h * 256 + wave * 64 + lane;
        srow[h] = D >> 3;
        scol[h] = ((D & 7) ^ (srow[h] & 7)) * 8;
        sdst[h] = (h * 256 + wave * 64) * 8;
    }

    f32x4 acc[4][4] = {};

    for (int kt = 0; kt < K; kt += 64) {
        #pragma unroll
        for (int h = 0; h < 4; ++h) {
            gl_lds16(&A[(size_t)(row0 + srow[h]) * K + kt + scol[h]], &As[sdst[h]]);
            gl_lds16(&Bt[(size_t)(col0 + srow[h]) * K + kt + scol[h]], &Bs[sdst[h]]);
        }
        __syncthreads();
        #pragma unroll
        for (int kk = 0; kk < 2; ++kk) {
            short8 af[4], bf[4];
            #pragma unroll
            for (int i = 0; i < 4; ++i) {
                int r = wm * 64 + i * 16 + l15;
                af[i] = *(const short8*)&As[r * 64 + (((kk * 4 + quad) ^ (r & 7)) * 8)];
            }
            #pragma unroll
            for (int j = 0; j < 4; ++j) {
                int r = wn * 64 + j * 16 + l15;
                bf[j] = *(const short8*)&Bs[r * 64 + (((kk * 4 + quad) ^ (r & 7)) * 8)];
            }
            if (isV) {
                #pragma unroll
                for (int i = 0; i < 4; ++i)
                    #pragma unroll
                    for (int j = 0; j < 4; ++j)
                        acc[i][j] = MFMA_B16(af[i], bf[j], acc[i][j]);  // C
            } else {
                #pragma unroll
                for (int i = 0; i < 4; ++i)
                    #pragma unroll
                    for (int j = 0; j < 4; ++j)
                        acc[i][j] = MFMA_B16(bf[j], af[i], acc[i][j]);  // C^T
            }
        }
        __syncthreads();
    }

    const int b = row0 >> 11;
    const int s0 = row0 & 2047;
    const float* bb = bias + col0 + wn * 64;

    if (!isV) {
        const int which = blockIdx.x >> 3;  // 0=Q, 1=K
        unsigned short* dst = which ? k : q;
        const float scale = which ? 1.0f : 0.1803368867f;  // 1/8 * log2(e) for Q
        const int hh = ((blockIdx.x & 7) << 1) + wn;
        #pragma unroll
        for (int i = 0; i < 4; ++i) {
            const int s = s0 + wm * 64 + i * 16 + l15;
            unsigned short* drow = dst + ((size_t)((b * 16 + hh) * 2048 + s)) * 64;
            #pragma unroll
            for (int j = 0; j < 4; ++j) {
                float4 b4 = ((const float4*)bb)[j * 4 + quad];
                uint2 pv;
                pv.x = pk_bf16((acc[i][j][0] + b4.x) * scale, (acc[i][j][1] + b4.y) * scale);
                pv.y = pk_bf16((acc[i][j][2] + b4.z) * scale, (acc[i][j][3] + b4.w) * scale);
                *(uint2*)&drow[j * 16 + quad * 4] = pv;
            }
        }
    } else {
        const int hh = ((blockIdx.x - 16) << 1) + wn;
        #pragma unroll
        for (int j = 0; j < 4; ++j) {
            const int d = j * 16 + l15;
            const float bv = bb[d];
            unsigned short* drow = vT + ((size_t)((b * 16 + hh) * 64 + d)) * 2048 + s0;
            #pragma unroll
            for (int i = 0; i < 4; ++i) {
                uint2 pv;
                pv.x = pk_bf16(acc[i][j][0] + bv, acc[i][j][1] + bv);
                pv.y = pk_bf16(acc[i][j][2] + bv, acc[i][j][3] + bv);
                *(uint2*)&drow[wm * 64 + i * 16 + quad * 4] = pv;
            }
        }
    }
}

// ---------------- proj GEMM: out[4096x1024] fp32 = A * Bt^T + bias ----------------
__global__ __launch_bounds__(256) void gemm_proj_kernel(const unsigned short* __restrict__ A,
                                                        const unsigned short* __restrict__ Bt,
                                                        const float* __restrict__ bias,
                                                        float* __restrict__ out) {
    __shared__ unsigned short As[128 * 64];
    __shared__ unsigned short Bs[64 * 64];
    const int tid = threadIdx.x;
    const int lane = tid & 63, wave = tid >> 6;
    const int l15 = lane & 15, quad = lane >> 4;
    const int wm = wave >> 1, wn = wave & 1;
    const int row0 = blockIdx.y * 128, col0 = blockIdx.x * 64;
    const int K = 1024;

    int srow[4], scol[4], sdst[4];
    #pragma unroll
    for (int h = 0; h < 4; ++h) {
        int D = h * 256 + wave * 64 + lane;
        srow[h] = D >> 3;
        scol[h] = ((D & 7) ^ (srow[h] & 7)) * 8;
        sdst[h] = (h * 256 + wave * 64) * 8;
    }

    f32x4 acc[4][2] = {};

    for (int kt = 0; kt < K; kt += 64) {
        #pragma unroll
        for (int h = 0; h < 4; ++h)
            gl_lds16(&A[(size_t)(row0 + srow[h]) * K + kt + scol[h]], &As[sdst[h]]);
        #pragma unroll
        for (int h = 0; h < 2; ++h)
            gl_lds16(&Bt[(size_t)(col0 + srow[h]) * K + kt + scol[h]], &Bs[sdst[h]]);
        __syncthreads();
        #pragma unroll
        for (int kk = 0; kk < 2; ++kk) {
            short8 af[4], bf[2];
            #pragma unroll
            for (int i = 0; i < 4; ++i) {
                int r = wm * 64 + i * 16 + l15;
                af[i] = *(const short8*)&As[r * 64 + (((kk * 4 + quad) ^ (r & 7)) * 8)];
            }
            #pragma unroll
            for (int j = 0; j < 2; ++j) {
                int r = wn * 32 + j * 16 + l15;
                bf[j] = *(const short8*)&Bs[r * 64 + (((kk * 4 + quad) ^ (r & 7)) * 8)];
            }
            #pragma unroll
            for (int i = 0; i < 4; ++i)
                #pragma unroll
                for (int j = 0; j < 2; ++j)
                    acc[i][j] = MFMA_B16(bf[j], af[i], acc[i][j]);  // C^T
        }
        __syncthreads();
    }

    const float* bb = bias + col0 + wn * 32;
    #pragma unroll
    for (int i = 0; i < 4; ++i) {
        const int row = row0 + wm * 64 + i * 16 + l15;
        #pragma unroll
        for (int j = 0; j < 2; ++j) {
            float4 b4 = ((const float4*)bb)[j * 4 + quad];
            float4 ov;
            ov.x = acc[i][j][0] + b4.x;
            ov.y = acc[i][j][1] + b4.y;
            ov.z = acc[i][j][2] + b4.z;
            ov.w = acc[i][j][3] + b4.w;
            *(float4*)&out[(size_t)row * 1024 + col0 + wn * 32 + j * 16 + quad * 4] = ov;
        }
    }
}

// ---------------- flash attention R9: 64-row tiles, 2 waves/block, 32 q-rows/wave ----
// 1024 blocks (R7 balanced map), 128 threads. Wave w owns within-tile rows [w*32, w*32+32)
// as subtiles A (+l15) and B (+16+l15); each K/V LDS fragment feeds both subtiles.
__global__ __launch_bounds__(128) void attn_kernel(const unsigned short* __restrict__ Q,
                                                   const unsigned short* __restrict__ Kg,
                                                   const unsigned short* __restrict__ Vt,
                                                   const int* __restrict__ idx,
                                                   const float* __restrict__ weight,
                                                   const int* __restrict__ forcing,
                                                   unsigned short* __restrict__ O) {
    __shared__ unsigned short Ks[2][4096];
    __shared__ unsigned short Vs[2][4096];
    __shared__ unsigned short Pw[2][2048];   // per-wave: sub A at 0, sub B at 1024

    const int tid = threadIdx.x;
    const int lane = tid & 63, wave = tid >> 6;   // 2 waves
    const int l15 = lane & 15, quad = lane >> 4;
    const int bid = blockIdx.x;
    // balanced tile map (R3/R7): per-CU iteration sums ~equal; bh groups a head per XCD
    const int u = bid >> 5, a = u & 7, qg = u >> 3;
    const int t = (qg == 0) ? (31 - a) : (qg == 1) ? (16 + a) : (qg == 2) ? (15 - a) : a;
    const int bh = bid & 31;
    const int b = bh >> 4, hh = bh & 15;
    const unsigned short* Qb = Q + (size_t)bh * 2048 * 64;
    const unsigned short* Kh = Kg + (size_t)bh * 2048 * 64;
    const unsigned short* Vh = Vt + (size_t)bh * 2048 * 64;

    const int idxb = idx[b];
    const float lw = (forcing[0] != 0) ? __log2f(weight[0]) : 0.0f;

    // staging: wave w, instr j (0..3) covers chunks (j*2+w)*64 + lane of each 8KB tile
    int rS[4], cS[4], dstc[4];
    #pragma unroll
    for (int j = 0; j < 4; ++j) {
        int c = (j * 2 + wave) * 64 + lane;
        rS[j] = c >> 3;
        cS[j] = (c & 7) ^ (rS[j] & 7);
        dstc[j] = ((j * 2 + wave) * 64) * 8;   // wave-uniform ushort offset
    }

    const int q0 = t * 64 + wave * 32;
    const int qrowA = q0 + l15;
    const int qrowB = q0 + 16 + l15;

    short8 aqA0 = *(const short8*)&Qb[(q0 + l15) * 64 + quad * 8];
    short8 aqA1 = *(const short8*)&Qb[(q0 + l15) * 64 + 32 + quad * 8];
    short8 aqB0 = *(const short8*)&Qb[(q0 + 16 + l15) * 64 + quad * 8];
    short8 aqB1 = *(const short8*)&Qb[(q0 + 16 + l15) * 64 + 32 + quad * 8];

    const short8 ones8 = {0x3F80, 0x3F80, 0x3F80, 0x3F80, 0x3F80, 0x3F80, 0x3F80, 0x3F80};

    f32x4 oA[4] = {}, oB[4] = {};
    f32x4 lsA = {}, lsB = {};

    const int nkb = t + 1;

    {   // prologue: stage block 0 into buf 0
        #pragma unroll
        for (int j = 0; j < 4; ++j) {
            gl_lds16(Kh + (size_t)rS[j] * 64 + cS[j] * 8,   &Ks[0][dstc[j]]);
            gl_lds16(Vh + (size_t)rS[j] * 2048 + cS[j] * 8, &Vs[0][dstc[j]]);
        }
    }
    __syncthreads();

    unsigned short* const pwb = &Pw[wave][0];
    const int pwr = l15 * 64;
    const int pa7 = l15 & 7;

    for (int kb = 0; kb < nkb; ++kb) {
        const int cur = kb & 1;
        const int kbase = kb * 64;
        if (kb + 1 < nkb) {
            const int nb = kbase + 64;
            #pragma unroll
            for (int j = 0; j < 4; ++j) {
                gl_lds16(Kh + (size_t)(nb + rS[j]) * 64 + cS[j] * 8,   &Ks[cur ^ 1][dstc[j]]);
                gl_lds16(Vh + (size_t)rS[j] * 2048 + nb + cS[j] * 8,   &Vs[cur ^ 1][dstc[j]]);
            }
        }

        // ---- forcing C-init (key-dependent, shared by subtiles) ----
        const bool fullF = (kbase >= idxb);
        const bool bndF = (!fullF) && (kbase + 63 >= idxb);
        const float zu = fullF ? lw : 0.0f;
        f32x4 zi[4];
        #pragma unroll
        for (int kt = 0; kt < 4; ++kt) {
            if (!bndF) {
                zi[kt][0] = zu; zi[kt][1] = zu; zi[kt][2] = zu; zi[kt][3] = zu;
            } else {
                #pragma unroll
                for (int r = 0; r < 4; ++r)
                    zi[kt][r] = (kbase + kt * 16 + quad * 4 + r >= idxb) ? lw : 0.0f;
            }
        }

        const bool diag = (kb + 1 == nkb);

        // ---- subtile A: S^T, mask, exp2, pack -> LDS ----
        {
            f32x4 sA[4];
            #pragma unroll
            for (int kt = 0; kt < 4; ++kt) {
                const int row = kt * 16 + l15;
                short8 k0 = *(const short8*)&Ks[cur][row * 64 + ((quad ^ (row & 7)) * 8)];
                short8 k1 = *(const short8*)&Ks[cur][row * 64 + (((4 + quad) ^ (row & 7)) * 8)];
                f32x4 z = zi[kt];
                z = MFMA_B16(k0, aqA0, z);
                z = MFMA_B16(k1, aqA1, z);
                sA[kt] = z;
            }
            if (diag) {
                #pragma unroll
                for (int kt = 0; kt < 4; ++kt)
                    #pragma unroll
                    for (int r = 0; r < 4; ++r)
                        if (kbase + kt * 16 + quad * 4 + r > qrowA) sA[kt][r] = -3.0e38f;
            }
            #pragma unroll
            for (int kt = 0; kt < 4; ++kt) {
                #pragma unroll
                for (int r = 0; r < 4; ++r) sA[kt][r] = EXP2(sA[kt][r]);
                unsigned int* pw = (unsigned int*)&pwb[pwr +
                    (((kt * 2 + (quad >> 1)) ^ pa7) * 8) + (quad & 1) * 4];
                pw[0] = pk_bf16(sA[kt][0], sA[kt][1]);
                pw[1] = pk_bf16(sA[kt][2], sA[kt][3]);
            }
        }
        // ---- subtile B ----
        {
            f32x4 sB[4];
            #pragma unroll
            for (int kt = 0; kt < 4; ++kt) {
                const int row = kt * 16 + l15;
                short8 k0 = *(const short8*)&Ks[cur][row * 64 + ((quad ^ (row & 7)) * 8)];
                short8 k1 = *(const short8*)&Ks[cur][row * 64 + (((4 + quad) ^ (row & 7)) * 8)];
                f32x4 z = zi[kt];
                z = MFMA_B16(k0, aqB0, z);
                z = MFMA_B16(k1, aqB1, z);
                sB[kt] = z;
            }
            if (diag) {
                #pragma unroll
                for (int kt = 0; kt < 4; ++kt)
                    #pragma unroll
                    for (int r = 0; r < 4; ++r)
                        if (kbase + kt * 16 + quad * 4 + r > qrowB) sB[kt][r] = -3.0e38f;
            }
            #pragma unroll
            for (int kt = 0; kt < 4; ++kt) {
                #pragma unroll
                for (int r = 0; r < 4; ++r) sB[kt][r] = EXP2(sB[kt][r]);
                unsigned int* pw = (unsigned int*)&pwb[1024 + pwr +
                    (((kt * 2 + (quad >> 1)) ^ pa7) * 8) + (quad & 1) * 4];
                pw[0] = pk_bf16(sB[kt][0], sB[kt][1]);
                pw[1] = pk_bf16(sB[kt][2], sB[kt][3]);
            }
        }

        // ---- B-frags + lsum ----
        short8 bpA0 = *(const short8*)&pwb[pwr + ((quad ^ pa7) * 8)];
        short8 bpA1 = *(const short8*)&pwb[pwr + (((4 + quad) ^ pa7) * 8)];
        short8 bpB0 = *(const short8*)&pwb[1024 + pwr + ((quad ^ pa7) * 8)];
        short8 bpB1 = *(const short8*)&pwb[1024 + pwr + (((4 + quad) ^ pa7) * 8)];
        lsA = MFMA_B16(ones8, bpA0, lsA);
        lsA = MFMA_B16(ones8, bpA1, lsA);
        lsB = MFMA_B16(ones8, bpB0, lsB);
        lsB = MFMA_B16(ones8, bpB1, lsB);

        // ---- O^T += V^T P^T (V fragments read once, used by both subtiles) ----
        #pragma unroll
        for (int dt = 0; dt < 4; ++dt) {
            const int row = dt * 16 + l15;
            short8 vf0 = *(const short8*)&Vs[cur][row * 64 + ((quad ^ (row & 7)) * 8)];
            short8 vf1 = *(const short8*)&Vs[cur][row * 64 + (((4 + quad) ^ (row & 7)) * 8)];
            f32x4 ooA = oA[dt];
            ooA = MFMA_B16(vf0, bpA0, ooA);
            ooA = MFMA_B16(vf1, bpA1, ooA);
            oA[dt] = ooA;
            f32x4 ooB = oB[dt];
            ooB = MFMA_B16(vf0, bpB0, ooB);
            ooB = MFMA_B16(vf1, bpB1, ooB);
            oB[dt] = ooB;
        }

        __syncthreads();
    }

    // ---- epilogue: O^T -> O via wave-private LDS transpose (K buffers dead) ----
    unsigned short* sc = &Ks[0][0] + wave * 1152;  // 16 rows x 72 stride, wave-private
    {
        const float inv = 1.0f / lsA[0];
        #pragma unroll
        for (int dt = 0; dt < 4; ++dt)
            #pragma unroll
            for (int r = 0; r < 4; ++r)
                sc[l15 * 72 + dt * 16 + quad * 4 + r] = f2bf(oA[dt][r] * inv);
        const size_t rowoff = ((size_t)(b * 2048 + q0 + l15)) * 1024 + hh * 64;
        #pragma unroll
        for (int h = 0; h < 2; ++h) {
            short8 v8 = *(const short8*)&sc[l15 * 72 + quad * 16 + h * 8];
            *(short8*)&O[rowoff + quad * 16 + h * 8] = v8;
        }
    }
    {
        const float inv = 1.0f / lsB[0];
        #pragma unroll
        for (int dt = 0; dt < 4; ++dt)
            #pragma unroll
            for (int r = 0; r < 4; ++r)
                sc[l15 * 72 + dt * 16 + quad * 4 + r] = f2bf(oB[dt][r] * inv);
        const size_t rowoff = ((size_t)(b * 2048 + q0 + 16 + l15)) * 1024 + hh * 64;
        #pragma unroll
        for (int h = 0; h < 2; ++h) {
            short8 v8 = *(const short8*)&sc[l15 * 72 + quad * 16 + h * 8];
            *(short8*)&O[rowoff + quad * 16 + h * 8] = v8;
        }
    }
}

extern "C" void kernel_launch(void* const* d_in, const int* in_sizes, int n_in,
                              void* d_out, int out_size, void* d_ws, size_t ws_size,
                              hipStream_t stream) {
    const float* x        = (const float*)d_in[0];
    const int*   idx      = (const int*)d_in[1];
    const float* weight   = (const float*)d_in[2];
    const int*   forcing  = (const int*)d_in[3];
    const float* w_qkv    = (const float*)d_in[4];
    const float* b_qkv    = (const float*)d_in[5];
    const float* w_proj   = (const float*)d_in[6];
    const float* b_proj   = (const float*)d_in[7];
    float* out = (float*)d_out;

    char* ws = (char*)d_ws;
    unsigned short* xb      = (unsigned short*)(ws);              // 8 MB (reused: attn_out)
    unsigned short* wqkvT   = (unsigned short*)(ws + 8388608);    // 6 MB
    unsigned short* wprojT  = (unsigned short*)(ws + 14680064);   // 2 MB
    unsigned short* qbuf    = (unsigned short*)(ws + 16777216);   // 8 MB
    unsigned short* kbuf    = (unsigned short*)(ws + 25165824);   // 8 MB
    unsigned short* vTbuf   = (unsigned short*)(ws + 33554432);   // 8 MB
    unsigned short* attn_out = xb;  // xb dead after gemm_qkv

    prep_kernel<<<8192, 256, 0, stream>>>((const float4*)x, (ushort4*)xb,
                                          w_qkv, wqkvT, w_proj, wprojT);
    gemm_qkv_kernel<<<dim3(24, 32), 256, 0, stream>>>(xb, wqkvT, b_qkv, qbuf, kbuf, vTbuf);
    attn_kernel<<<1024, 128, 0, stream>>>(qbuf, kbuf, vTbuf, idx, weight, forcing, attn_out);
    gemm_proj_kernel<<<dim3(16, 32), 256, 0, stream>>>(attn_out, wprojT, b_proj, out);
}